// Round 11
// baseline (501.715 us; speedup 1.0000x reference)
//
#include <hip/hip_runtime.h>
#include <hip/hip_bf16.h>
#include <hip/hip_cooperative_groups.h>

namespace cg = cooperative_groups;

// MahalanobisDistanceLayer: B=8192, D=64.
// q = E @ E^T with E = (a-b) * rsqrt(var_per_feature(concat(a,b)+eps));
// out[i] = sum_j (q<0 ? 0 : sqrt(q)) + B*EPS_OUT for (anchor,positive), (anchor,negative).
//
// Split-bf16: E = Ehi + Elo -> K=192 bf16 GEMM on MFMA. Symmetric tile-pair scheme
// halves FLOPs. Phases: A stats-partials, B reduce, C prep(EHL), D mdist GEMM.
// Primary: ONE cooperative launch (512x256, 32KB LDS -> co-residency safe) with
// __threadfence() around grid.sync for cross-XCD visibility. Fallback on launch
// error: 4 regular dispatches with the same phase bodies.

typedef short bf16x8 __attribute__((ext_vector_type(8)));
typedef unsigned short u16x8 __attribute__((ext_vector_type(8)));
typedef float f32x4 __attribute__((ext_vector_type(4)));

#define BROWS 8192
#define DFEAT 64
#define NCO   16384
#define EPS_IN  1e-4f
#define EPS_OUT 1e-6f

// ---- workspace layout (floats) ----
// [0, 384)          : stats (Sa,Qa,Sp,Qp,Sn,Qn x 64), written by phase B
// [512, 512+196608) : part[v][b] v-major partials (384 x 512)
// [197120, +1M fl)  : EHL, 2 pairs x 8192 rows x 128 bf16 (row=[hi|lo], 256B),
//                     16B-chunk index XOR-swizzled by (row&7)
#define WS_PART_F 512
#define WS_EHL_F  197120
#define EHL_PAIR_USHORTS ((size_t)BROWS * 128)

static __device__ inline unsigned short f2bf_rne(float x) {
  unsigned u = __float_as_uint(x);
  unsigned r = (u + 0x7FFF + ((u >> 16) & 1)) >> 16;
  return (unsigned short)r;
}
static __device__ inline float bf2f(unsigned short s) {
  return __uint_as_float(((unsigned)s) << 16);
}

#define GLOAD(gsrc, ldst)                                                  \
  __builtin_amdgcn_global_load_lds(                                        \
      (const __attribute__((address_space(1))) void*)(gsrc),               \
      (__attribute__((address_space(3))) void*)(ldst), 16, 0, 0)

// ---------------------------------------------------------------------------
// Phase A: per-block stats partials. 512 blocks; one float4/thread/array.
static __device__ __forceinline__ void phaseA(
    const float* __restrict__ a, const float* __restrict__ p,
    const float* __restrict__ n, float* __restrict__ part,
    unsigned char* smem, int bid, int tid) {
  float* acc = (float*)smem;                 // [384]
  for (int v = tid; v < 384; v += 256) acc[v] = 0.f;
  __syncthreads();
  size_t g = (size_t)bid * 256 + tid;
  float4 va = ((const float4*)a)[g];
  float4 vp = ((const float4*)p)[g];
  float4 vn = ((const float4*)n)[g];
  float s[3][4], q[3][4];
  float ea[4] = {va.x, va.y, va.z, va.w};
  float ep[4] = {vp.x, vp.y, vp.z, vp.w};
  float en[4] = {vn.x, vn.y, vn.z, vn.w};
  #pragma unroll
  for (int f = 0; f < 4; ++f) {
    float x0 = ea[f] + EPS_IN; s[0][f] = x0; q[0][f] = x0 * x0;
    float x1 = ep[f] + EPS_IN; s[1][f] = x1; q[1][f] = x1 * x1;
    float x2 = en[f] + EPS_IN; s[2][f] = x2; q[2][f] = x2 * x2;
  }
  #pragma unroll
  for (int g2 = 0; g2 < 3; ++g2)
    #pragma unroll
    for (int f = 0; f < 4; ++f) {
      float vs = s[g2][f], vq = q[g2][f];
      vs += __shfl_xor(vs, 16); vs += __shfl_xor(vs, 32);
      vq += __shfl_xor(vq, 16); vq += __shfl_xor(vq, 32);
      s[g2][f] = vs; q[g2][f] = vq;
    }
  int lane = tid & 63;
  if (lane < 16) {
    int d0 = lane * 4;
    #pragma unroll
    for (int g2 = 0; g2 < 3; ++g2)
      #pragma unroll
      for (int f = 0; f < 4; ++f) {
        atomicAdd(&acc[(2 * g2) * 64 + d0 + f], s[g2][f]);
        atomicAdd(&acc[(2 * g2 + 1) * 64 + d0 + f], q[g2][f]);
      }
  }
  __syncthreads();
  for (int v = tid; v < 384; v += 256)
    part[(size_t)v * 512 + bid] = acc[v];
}

// Phase B: blocks 0..383 reduce 512 partials -> stats[v].
static __device__ __forceinline__ void phaseB(
    const float* __restrict__ part, float* __restrict__ stats,
    unsigned char* smem, int bid, int tid) {
  if (bid >= 384) return;
  float* red = (float*)smem;                 // [4]
  const float* pv = part + (size_t)bid * 512;
  float x = pv[tid] + pv[tid + 256];
  x += __shfl_xor(x, 1);  x += __shfl_xor(x, 2);
  x += __shfl_xor(x, 4);  x += __shfl_xor(x, 8);
  x += __shfl_xor(x, 16); x += __shfl_xor(x, 32);
  if ((tid & 63) == 0) red[tid >> 6] = x;
  __syncthreads();
  if (tid == 0) stats[bid] = red[0] + red[1] + red[2] + red[3];
}

// Phase C: inv_std inline; build EHL rows [hi|lo] bf16 swizzled; init out.
static __device__ __forceinline__ void phaseC(
    const float* __restrict__ a, const float* __restrict__ p,
    const float* __restrict__ n, const float* __restrict__ stats,
    unsigned short* __restrict__ EHL, float* __restrict__ out,
    unsigned char* smem, int bid, int tid) {
  float* is_s = (float*)smem;                // [64]
  int pair = bid >> 8;
  int tb   = bid & 255;
  if (tid < 32) out[bid * 32 + tid] = 8192.0f * EPS_OUT;
  if (tid < 64) {
    float sa = stats[tid], qa = stats[64 + tid];
    float sb = pair ? stats[256 + tid] : stats[128 + tid];
    float qb = pair ? stats[320 + tid] : stats[192 + tid];
    const float invN = 1.0f / (float)NCO;
    float m = (sa + sb) * invN;
    float v = (qa + qb) * invN - m * m;
    is_s[tid] = 1.0f / sqrtf(v);
  }
  __syncthreads();
  const float* bptr = pair ? n : p;
  unsigned short* dst = EHL + (size_t)pair * EHL_PAIR_USHORTS;
  int c0 = tid & 7;
  int rl = tid >> 3;
  int row = tb * 32 + rl;
  int d0 = c0 * 8;
  const float* ar = a    + (size_t)row * DFEAT + d0;
  const float* br = bptr + (size_t)row * DFEAT + d0;
  float4 a0 = *(const float4*)(ar);
  float4 a1 = *(const float4*)(ar + 4);
  float4 b0 = *(const float4*)(br);
  float4 b1 = *(const float4*)(br + 4);
  float e[8] = {a0.x - b0.x, a0.y - b0.y, a0.z - b0.z, a0.w - b0.w,
                a1.x - b1.x, a1.y - b1.y, a1.z - b1.z, a1.w - b1.w};
  u16x8 vh, vl;
  #pragma unroll
  for (int j = 0; j < 8; ++j) {
    float ej = e[j] * is_s[d0 + j];
    unsigned short hi = f2bf_rne(ej);
    vh[j] = hi;
    vl[j] = f2bf_rne(ej - bf2f(hi));
  }
  int cs = c0 ^ (row & 7);
  char* drow = (char*)dst + (size_t)row * 256;
  *(u16x8*)(drow + cs * 16)       = vh;
  *(u16x8*)(drow + (8 + cs) * 16) = vl;
}

// Phase D: symmetric MFMA GEMM, 32KB LDS (A staged then reused as 2x16KB B dbuf).
static __device__ __forceinline__ void phaseD(
    const unsigned short* __restrict__ EHL, float* __restrict__ out,
    unsigned char* smem, int bid, int tid) {
  unsigned char* sB0 = smem;                 // 16KB
  unsigned char* sB1 = smem + 16384;         // 16KB
  int sw  = (bid & 7) * 64 + (bid >> 3);     // bijective XCD swizzle (512 = 8*64)
  int pair  = sw >> 8;
  int ib    = (sw >> 2) & 63;
  int half  = (sw >> 1) & 1;
  int squad = sw & 1;
  const char* base = (const char*)(EHL + (size_t)pair * EHL_PAIR_USHORTS);
  const char* gA = base + (size_t)ib * 32768;
  int s0   = half + 2 * squad;
  int smax = (ib < 32) ? 32 : 31;
  int nT   = ((smax - s0) / 4 + 1) * 2;

  // stage A (32KB) into the whole smem
  #pragma unroll
  for (int r = 0; r < 8; ++r) {
    int off = r * 4096 + tid * 16;
    GLOAD(gA + off, smem + off);
  }
  __syncthreads();

  int lane = tid & 63, w = tid >> 6;
  int wr = w >> 1, wc = w & 1;               // wave tile: rows wr*64, cols wc*32
  int l15 = lane & 15, lg = lane >> 4;

  bf16x8 af[4][4];
  #pragma unroll
  for (int hk = 0; hk < 4; ++hk) {
    int c = ((hk >> 1) << 3) | ((hk & 1) << 2) | lg;
    #pragma unroll
    for (int m = 0; m < 4; ++m) {
      int r = wr * 64 + m * 16 + l15;
      int cs = c ^ (r & 7);
      af[hk][m] = *(const bf16x8*)(smem + r * 256 + cs * 16);
    }
  }
  __syncthreads();   // all af reads done -> smem free for B staging

  // stage B(0) -> sB0
  {
    const char* gB0 = base + (size_t)((ib + s0) & 63) * 32768;
    #pragma unroll
    for (int r = 0; r < 4; ++r) {
      int off = r * 4096 + tid * 16;
      GLOAD(gB0 + off, sB0 + off);
    }
  }
  __syncthreads();

  float rs[4][4];
  #pragma unroll
  for (int m = 0; m < 4; ++m)
    #pragma unroll
    for (int r = 0; r < 4; ++r) rs[m][r] = 0.f;

  const f32x4 zacc = {0.f, 0.f, 0.f, 0.f};
  const int AH[3] = {0, 0, 1};
  const int BH[3] = {0, 1, 0};

  for (int t = 0; t < nT; ++t) {
    unsigned char* wbuf = (t & 1) ? sB0 : sB1;        // gets B(t+1)
    const unsigned char* rbuf = (t & 1) ? sB1 : sB0;  // holds B(t)
    int s   = s0 + 4 * (t >> 1);
    int sub = t & 1;
    if (t + 1 < nT) {
      int tn = t + 1;
      int sn = s0 + 4 * (tn >> 1);
      const char* gs = base + (size_t)((ib + sn) & 63) * 32768 + (tn & 1) * 16384;
      #pragma unroll
      for (int r = 0; r < 4; ++r) {
        int off = r * 4096 + tid * 16;
        GLOAD(gs + off, wbuf + off);
      }
    }
    bf16x8 bf[4][2];
    #pragma unroll
    for (int hk = 0; hk < 4; ++hk) {
      int c = ((hk >> 1) << 3) | ((hk & 1) << 2) | lg;
      #pragma unroll
      for (int nn = 0; nn < 2; ++nn) {
        int r = wc * 32 + nn * 16 + l15;
        int cs = c ^ (r & 7);
        bf[hk][nn] = *(const bf16x8*)(rbuf + r * 256 + cs * 16);
      }
    }
    f32x4 acc[4][2];
    #pragma unroll
    for (int tt = 0; tt < 3; ++tt) {
      #pragma unroll
      for (int ks = 0; ks < 2; ++ks) {
        int ahk = (AH[tt] << 1) | ks;
        int bhk = (BH[tt] << 1) | ks;
        #pragma unroll
        for (int m = 0; m < 4; ++m) {
          #pragma unroll
          for (int nn = 0; nn < 2; ++nn)
            acc[m][nn] = __builtin_amdgcn_mfma_f32_16x16x32_bf16(
                af[ahk][m], bf[bhk][nn],
                (tt == 0 && ks == 0) ? zacc : acc[m][nn], 0, 0, 0);
        }
      }
    }
    if (s == 0) {
      #pragma unroll
      for (int m = 0; m < 4; ++m)
        #pragma unroll
        for (int nn = 0; nn < 2; ++nn)
          #pragma unroll
          for (int r = 0; r < 4; ++r)
            rs[m][r] += __builtin_amdgcn_sqrtf(fmaxf(acc[m][nn][r], 0.f));
    } else {
      float cq0 = 0.f, cq1 = 0.f;
      #pragma unroll
      for (int m = 0; m < 4; ++m)
        #pragma unroll
        for (int nn = 0; nn < 2; ++nn)
          #pragma unroll
          for (int r = 0; r < 4; ++r) {
            float f = __builtin_amdgcn_sqrtf(fmaxf(acc[m][nn][r], 0.f));
            rs[m][r] += f;
            if (nn == 0) cq0 += f; else cq1 += f;
          }
      cq0 += __shfl_xor(cq0, 16); cq0 += __shfl_xor(cq0, 32);
      cq1 += __shfl_xor(cq1, 16); cq1 += __shfl_xor(cq1, 32);
      if (lane < 16) {
        int jb = (ib + s) & 63;
        float* orow = &out[pair * BROWS + jb * 128 + sub * 64 + wc * 32 + l15];
        atomicAdd(orow, cq0);
        atomicAdd(orow + 16, cq1);
      }
    }
    __syncthreads();
  }

  #pragma unroll
  for (int m = 0; m < 4; ++m)
    #pragma unroll
    for (int r = 0; r < 4; ++r) {
      float v = rs[m][r];
      v += __shfl_xor(v, 1);
      v += __shfl_xor(v, 2);
      v += __shfl_xor(v, 4);
      v += __shfl_xor(v, 8);
      rs[m][r] = v;
    }
  if (l15 == 0) {
    int i0 = ib * 128 + wr * 64;
    #pragma unroll
    for (int m = 0; m < 4; ++m)
      #pragma unroll
      for (int r = 0; r < 4; ++r)
        atomicAdd(&out[pair * BROWS + i0 + m * 16 + lg * 4 + r], rs[m][r]);
  }
}

// ---------------------------------------------------------------------------
// Fused cooperative kernel.
__global__ __launch_bounds__(256, 2) void fused_kernel(
    const float* __restrict__ a, const float* __restrict__ p,
    const float* __restrict__ n, float* __restrict__ ws,
    float* __restrict__ out) {
  __shared__ __align__(16) unsigned char smem[32768];
  cg::grid_group grid = cg::this_grid();
  float* stats = ws;
  float* part  = ws + WS_PART_F;
  unsigned short* EHL = (unsigned short*)(ws + WS_EHL_F);
  int tid = threadIdx.x, bid = blockIdx.x;

  phaseA(a, p, n, part, smem, bid, tid);
  __threadfence();  grid.sync();  __threadfence();
  phaseB(part, stats, smem, bid, tid);
  __threadfence();  grid.sync();  __threadfence();
  phaseC(a, p, n, stats, EHL, out, smem, bid, tid);
  __threadfence();  grid.sync();  __threadfence();
  phaseD(EHL, out, smem, bid, tid);
}

// Split fallback kernels (regular launches).
__global__ __launch_bounds__(256, 2) void kA(
    const float* __restrict__ a, const float* __restrict__ p,
    const float* __restrict__ n, float* __restrict__ part) {
  __shared__ __align__(16) unsigned char smem[32768];
  phaseA(a, p, n, part, smem, blockIdx.x, threadIdx.x);
}
__global__ __launch_bounds__(256, 2) void kB(
    const float* __restrict__ part, float* __restrict__ stats) {
  __shared__ __align__(16) unsigned char smem[32768];
  phaseB(part, stats, smem, blockIdx.x, threadIdx.x);
}
__global__ __launch_bounds__(256, 2) void kC(
    const float* __restrict__ a, const float* __restrict__ p,
    const float* __restrict__ n, const float* __restrict__ stats,
    unsigned short* __restrict__ EHL, float* __restrict__ out) {
  __shared__ __align__(16) unsigned char smem[32768];
  phaseC(a, p, n, stats, EHL, out, smem, blockIdx.x, threadIdx.x);
}
__global__ __launch_bounds__(256, 2) void kD(
    const unsigned short* __restrict__ EHL, float* __restrict__ out) {
  __shared__ __align__(16) unsigned char smem[32768];
  phaseD(EHL, out, smem, blockIdx.x, threadIdx.x);
}

// ---------------------------------------------------------------------------
extern "C" void kernel_launch(void* const* d_in, const int* in_sizes, int n_in,
                              void* d_out, int out_size, void* d_ws, size_t ws_size,
                              hipStream_t stream) {
  const float* anchor   = (const float*)d_in[0];
  const float* positive = (const float*)d_in[1];
  const float* negative = (const float*)d_in[2];
  float* out = (float*)d_out;
  float* ws  = (float*)d_ws;
  float* stats = ws;
  float* part  = ws + WS_PART_F;
  unsigned short* EHL = (unsigned short*)(ws + WS_EHL_F);

  void* args[] = {(void*)&anchor, (void*)&positive, (void*)&negative,
                  (void*)&ws, (void*)&out};
  hipError_t err = hipLaunchCooperativeKernel((void*)fused_kernel, dim3(512),
                                              dim3(256), args, 0, stream);
  if (err != hipSuccess) {
    // fallback: same phases as 4 regular dispatches
    kA<<<512, 256, 0, stream>>>(anchor, positive, negative, part);
    kB<<<384, 256, 0, stream>>>(part, stats);
    kC<<<512, 256, 0, stream>>>(anchor, positive, negative, stats, EHL, out);
    kD<<<512, 256, 0, stream>>>(EHL, out);
  }
}

// Round 12
// 177.081 us; speedup vs baseline: 2.8333x; 2.8333x over previous
//
#include <hip/hip_runtime.h>
#include <hip/hip_bf16.h>

// MahalanobisDistanceLayer: B=8192, D=64.
// q = E @ E^T with E = (a-b) * rsqrt(var_per_feature(concat(a,b)+eps));
// out[i] = sum_j (q<0 ? 0 : sqrt(q)) + B*EPS_OUT for (anchor,positive), (anchor,negative).
//
// Split-bf16: E = Ehi + Elo -> K=192 bf16 GEMM on MFMA. Symmetric tile-pair scheme
// halves FLOPs: unordered 128-row tile pair {ib,(ib+s)&63} done once (s<=32, s=32 only
// ib<32); off-diag adds row-sums to ib-rows AND col-sums to jb-rows.
// 3 dispatches: stats(partials, no memset) -> prep(reduce+EHL) -> mdist.
// mdist: s-ring split 8 ways (s ≡ r mod 8) -> 1024 blocks = 4 blocks/CU for barrier overlap.

typedef short bf16x8 __attribute__((ext_vector_type(8)));
typedef unsigned short u16x8 __attribute__((ext_vector_type(8)));
typedef float f32x4 __attribute__((ext_vector_type(4)));

#define BROWS 8192
#define DFEAT 64
#define NCO   16384
#define EPS_IN  1e-4f
#define EPS_OUT 1e-6f
#define NPART 64

// ---- workspace layout (floats) ----
// [0, 24576)       : part[b][v] partials (64 blocks x 384), non-atomic
// [24576, +1M fl)  : EHL, 2 pairs x 8192 rows x 128 bf16 (row=[hi|lo], 256B),
//                    16B-chunk index XOR-swizzled by (row&7)
#define WS_EHL_F  24576
#define EHL_PAIR_USHORTS ((size_t)BROWS * 128)

static __device__ inline unsigned short f2bf_rne(float x) {
  unsigned u = __float_as_uint(x);
  unsigned r = (u + 0x7FFF + ((u >> 16) & 1)) >> 16;
  return (unsigned short)r;
}
static __device__ inline float bf2f(unsigned short s) {
  return __uint_as_float(((unsigned)s) << 16);
}

#define GLOAD(gsrc, ldst)                                                  \
  __builtin_amdgcn_global_load_lds(                                        \
      (const __attribute__((address_space(1))) void*)(gsrc),               \
      (__attribute__((address_space(3))) void*)(ldst), 16, 0, 0)

// ---------------------------------------------------------------------------
// Kernel A: per-block stats partials, NON-atomic (no zero-init needed).
// 64 blocks x 256 threads; block b covers rows [b*128, b*128+128): 8 float4/thread/array.
__global__ __launch_bounds__(256) void stats_kernel(
    const float* __restrict__ a, const float* __restrict__ p,
    const float* __restrict__ n, float* __restrict__ part) {
  __shared__ float acc[384];
  int tid = threadIdx.x;
  int bid = blockIdx.x;
  for (int v = tid; v < 384; v += 256) acc[v] = 0.f;
  __syncthreads();
  const float4* A4 = (const float4*)a;
  const float4* P4 = (const float4*)p;
  const float4* N4 = (const float4*)n;
  size_t base = (size_t)bid * 2048 + tid;
  float s[3][4] = {}, q[3][4] = {};
  #pragma unroll
  for (int k = 0; k < 8; ++k) {
    size_t idx = base + k * 256;
    float4 va = A4[idx], vp = P4[idx], vn = N4[idx];
    float ea[4] = {va.x, va.y, va.z, va.w};
    float ep[4] = {vp.x, vp.y, vp.z, vp.w};
    float en[4] = {vn.x, vn.y, vn.z, vn.w};
    #pragma unroll
    for (int f = 0; f < 4; ++f) {
      float x0 = ea[f] + EPS_IN; s[0][f] += x0; q[0][f] += x0 * x0;
      float x1 = ep[f] + EPS_IN; s[1][f] += x1; q[1][f] += x1 * x1;
      float x2 = en[f] + EPS_IN; s[2][f] += x2; q[2][f] += x2 * x2;
    }
  }
  // lanes t, t^16, t^32, t^48 share feature group d0 = 4*(t&15)
  #pragma unroll
  for (int g = 0; g < 3; ++g)
    #pragma unroll
    for (int f = 0; f < 4; ++f) {
      float vs = s[g][f], vq = q[g][f];
      vs += __shfl_xor(vs, 16); vs += __shfl_xor(vs, 32);
      vq += __shfl_xor(vq, 16); vq += __shfl_xor(vq, 32);
      s[g][f] = vs; q[g][f] = vq;
    }
  int lane = tid & 63;
  if (lane < 16) {
    int d0 = lane * 4;
    #pragma unroll
    for (int g = 0; g < 3; ++g)
      #pragma unroll
      for (int f = 0; f < 4; ++f) {
        atomicAdd(&acc[(2 * g) * 64 + d0 + f], s[g][f]);
        atomicAdd(&acc[(2 * g + 1) * 64 + d0 + f], q[g][f]);
      }
  }
  __syncthreads();
  for (int v = tid; v < 384; v += 256)
    part[(size_t)bid * 384 + v] = acc[v];
}

// ---------------------------------------------------------------------------
// Kernel B: reduce partials in-block -> inv_std; build EHL rows [hi|lo] bf16,
// 16B chunks XOR-swizzled by row&7; pre-load out with 8192*EPS_OUT.
// Grid: 2 pairs x 256 row-tiles (32 rows each) = 512 blocks x 256 threads.
__global__ __launch_bounds__(256) void prep_kernel(
    const float* __restrict__ a, const float* __restrict__ p,
    const float* __restrict__ n, const float* __restrict__ part,
    unsigned short* __restrict__ EHL, float* __restrict__ out) {
  __shared__ float stats_s[384];
  __shared__ float is_s[64];
  int pair = blockIdx.x >> 8;
  int tb   = blockIdx.x & 255;
  int tid  = threadIdx.x;
  if (tid < 32) out[blockIdx.x * 32 + tid] = 8192.0f * EPS_OUT;
  // reduce part[0..63][v] -> stats_s[v]  (coalesced per iteration)
  {
    float s1 = 0.f, s2 = 0.f;
    for (int b = 0; b < NPART; ++b) {
      const float* pb = part + (size_t)b * 384;
      s1 += pb[tid];
      if (tid < 128) s2 += pb[256 + tid];
    }
    stats_s[tid] = s1;
    if (tid < 128) stats_s[256 + tid] = s2;
  }
  __syncthreads();
  if (tid < 64) {
    float sa = stats_s[tid], qa = stats_s[64 + tid];
    float sb = pair ? stats_s[256 + tid] : stats_s[128 + tid];
    float qb = pair ? stats_s[320 + tid] : stats_s[192 + tid];
    const float invN = 1.0f / (float)NCO;
    float m = (sa + sb) * invN;
    float v = (qa + qb) * invN - m * m;
    is_s[tid] = 1.0f / sqrtf(v);
  }
  __syncthreads();
  const float* bptr = pair ? n : p;
  unsigned short* dst = EHL + (size_t)pair * EHL_PAIR_USHORTS;
  int c0 = tid & 7;          // chunk within row (8 bf16 = 16B)
  int rl = tid >> 3;         // row within block (0..31)
  int row = tb * 32 + rl;
  int d0 = c0 * 8;
  const float* ar = a    + (size_t)row * DFEAT + d0;
  const float* br = bptr + (size_t)row * DFEAT + d0;
  float4 a0 = *(const float4*)(ar);
  float4 a1 = *(const float4*)(ar + 4);
  float4 b0 = *(const float4*)(br);
  float4 b1 = *(const float4*)(br + 4);
  float e[8] = {a0.x - b0.x, a0.y - b0.y, a0.z - b0.z, a0.w - b0.w,
                a1.x - b1.x, a1.y - b1.y, a1.z - b1.z, a1.w - b1.w};
  u16x8 vh, vl;
  #pragma unroll
  for (int j = 0; j < 8; ++j) {
    float ej = e[j] * is_s[d0 + j];
    unsigned short hi = f2bf_rne(ej);
    vh[j] = hi;
    vl[j] = f2bf_rne(ej - bf2f(hi));
  }
  int cs = c0 ^ (row & 7);
  char* drow = (char*)dst + (size_t)row * 256;
  *(u16x8*)(drow + cs * 16)       = vh;   // hi chunk
  *(u16x8*)(drow + (8 + cs) * 16) = vl;   // lo chunk
}

// ---------------------------------------------------------------------------
// Kernel C: symmetric MFMA GEMM. Block = (pair, ib, r): A tile (128 rows)
// persistent in registers; s = r, r+8, ... <= smax; each tile = two 64-row
// B substeps (16KB, double-buffered in the 32KB LDS after A-frag extraction).
// Grid: 2 x 64 x 8 = 1024 blocks x 256 threads, 32KB LDS -> 4 blocks/CU.
__global__ __launch_bounds__(256, 4) void mdist_mfma(
    const unsigned short* __restrict__ EHL, float* __restrict__ out) {
  __shared__ __align__(16) unsigned char smem[32768];
  unsigned char* sB0 = smem;
  unsigned char* sB1 = smem + 16384;
  int bid = blockIdx.x;
  int sw  = (bid & 7) * 128 + (bid >> 3);  // XCD swizzle (1024 = 8*128)
  int pair = sw >> 9;
  int ib   = (sw >> 3) & 63;
  int r0   = sw & 7;                       // s ≡ r0 (mod 8)
  const char* base = (const char*)(EHL + (size_t)pair * EHL_PAIR_USHORTS);
  const char* gA = base + (size_t)ib * 32768;
  int tid = threadIdx.x;
  int smax = (ib < 32) ? 32 : 31;
  int nT   = ((smax - r0) / 8 + 1) * 2;    // substeps (8 or 10)

  // stage A (32KB) into the whole smem
  #pragma unroll
  for (int rr = 0; rr < 8; ++rr) {
    int off = rr * 4096 + tid * 16;
    GLOAD(gA + off, smem + off);
  }
  __syncthreads();

  int lane = tid & 63, w = tid >> 6;
  int wr = w >> 1, wc = w & 1;             // wave tile: rows wr*64, cols wc*32
  int l15 = lane & 15, lg = lane >> 4;

  // A fragments, resident for whole kernel: af[hk][m], hk = (half_sel<<1)|ks
  bf16x8 af[4][4];
  #pragma unroll
  for (int hk = 0; hk < 4; ++hk) {
    int c = ((hk >> 1) << 3) | ((hk & 1) << 2) | lg;
    #pragma unroll
    for (int m = 0; m < 4; ++m) {
      int rr = wr * 64 + m * 16 + l15;
      int cs = c ^ (rr & 7);
      af[hk][m] = *(const bf16x8*)(smem + rr * 256 + cs * 16);
    }
  }
  __syncthreads();   // all af reads done -> smem free for B staging

  // stage B substep 0 -> sB0
  {
    const char* gB0 = base + (size_t)((ib + r0) & 63) * 32768;
    #pragma unroll
    for (int rr = 0; rr < 4; ++rr) {
      int off = rr * 4096 + tid * 16;
      GLOAD(gB0 + off, sB0 + off);
    }
  }
  __syncthreads();

  float rs[4][4];
  #pragma unroll
  for (int m = 0; m < 4; ++m)
    #pragma unroll
    for (int rr = 0; rr < 4; ++rr) rs[m][rr] = 0.f;

  const f32x4 zacc = {0.f, 0.f, 0.f, 0.f};
  const int AH[3] = {0, 0, 1};
  const int BH[3] = {0, 1, 0};

  for (int t = 0; t < nT; ++t) {
    unsigned char* wbuf = (t & 1) ? sB0 : sB1;        // receives B(t+1)
    const unsigned char* rbuf = (t & 1) ? sB1 : sB0;  // holds B(t)
    int s   = r0 + 8 * (t >> 1);
    int sub = t & 1;
    if (t + 1 < nT) {
      int tn = t + 1;
      int sn = r0 + 8 * (tn >> 1);
      const char* gs = base + (size_t)((ib + sn) & 63) * 32768 + (tn & 1) * 16384;
      #pragma unroll
      for (int rr = 0; rr < 4; ++rr) {
        int off = rr * 4096 + tid * 16;
        GLOAD(gs + off, wbuf + off);
      }
    }
    bf16x8 bf[4][2];
    #pragma unroll
    for (int hk = 0; hk < 4; ++hk) {
      int c = ((hk >> 1) << 3) | ((hk & 1) << 2) | lg;
      #pragma unroll
      for (int nn = 0; nn < 2; ++nn) {
        int rr = wc * 32 + nn * 16 + l15;
        int cs = c ^ (rr & 7);
        bf[hk][nn] = *(const bf16x8*)(rbuf + rr * 256 + cs * 16);
      }
    }
    f32x4 acc[4][2];
    #pragma unroll
    for (int tt = 0; tt < 3; ++tt) {
      #pragma unroll
      for (int ks = 0; ks < 2; ++ks) {
        int ahk = (AH[tt] << 1) | ks;
        int bhk = (BH[tt] << 1) | ks;
        #pragma unroll
        for (int m = 0; m < 4; ++m) {
          #pragma unroll
          for (int nn = 0; nn < 2; ++nn)
            acc[m][nn] = __builtin_amdgcn_mfma_f32_16x16x32_bf16(
                af[ahk][m], bf[bhk][nn],
                (tt == 0 && ks == 0) ? zacc : acc[m][nn], 0, 0, 0);
        }
      }
    }
    // epilogue: f = sqrt(max(q,0)); rows always; cols for off-diag tiles
    if (s == 0) {
      #pragma unroll
      for (int m = 0; m < 4; ++m)
        #pragma unroll
        for (int nn = 0; nn < 2; ++nn)
          #pragma unroll
          for (int rr = 0; rr < 4; ++rr)
            rs[m][rr] += __builtin_amdgcn_sqrtf(fmaxf(acc[m][nn][rr], 0.f));
    } else {
      float cq0 = 0.f, cq1 = 0.f;
      #pragma unroll
      for (int m = 0; m < 4; ++m)
        #pragma unroll
        for (int nn = 0; nn < 2; ++nn)
          #pragma unroll
          for (int rr = 0; rr < 4; ++rr) {
            float f = __builtin_amdgcn_sqrtf(fmaxf(acc[m][nn][rr], 0.f));
            rs[m][rr] += f;
            if (nn == 0) cq0 += f; else cq1 += f;
          }
      cq0 += __shfl_xor(cq0, 16); cq0 += __shfl_xor(cq0, 32);
      cq1 += __shfl_xor(cq1, 16); cq1 += __shfl_xor(cq1, 32);
      if (lane < 16) {
        int jb = (ib + s) & 63;
        float* orow = &out[pair * BROWS + jb * 128 + sub * 64 + wc * 32 + l15];
        atomicAdd(orow, cq0);
        atomicAdd(orow + 16, cq1);
      }
    }
    __syncthreads();
  }

  // final row-sum reduce over the 16 col-lanes, one atomic per row per wave
  #pragma unroll
  for (int m = 0; m < 4; ++m)
    #pragma unroll
    for (int rr = 0; rr < 4; ++rr) {
      float v = rs[m][rr];
      v += __shfl_xor(v, 1);
      v += __shfl_xor(v, 2);
      v += __shfl_xor(v, 4);
      v += __shfl_xor(v, 8);
      rs[m][rr] = v;
    }
  if (l15 == 0) {
    int i0 = ib * 128 + wr * 64;
    #pragma unroll
    for (int m = 0; m < 4; ++m)
      #pragma unroll
      for (int rr = 0; rr < 4; ++rr)
        atomicAdd(&out[pair * BROWS + i0 + m * 16 + lg * 4 + rr], rs[m][rr]);
  }
}

// ---------------------------------------------------------------------------
extern "C" void kernel_launch(void* const* d_in, const int* in_sizes, int n_in,
                              void* d_out, int out_size, void* d_ws, size_t ws_size,
                              hipStream_t stream) {
  const float* anchor   = (const float*)d_in[0];
  const float* positive = (const float*)d_in[1];
  const float* negative = (const float*)d_in[2];
  float* out = (float*)d_out;
  float* ws  = (float*)d_ws;

  float* part = ws;
  unsigned short* EHL = (unsigned short*)(ws + WS_EHL_F);

  stats_kernel<<<64, 256, 0, stream>>>(anchor, positive, negative, part);
  prep_kernel<<<512, 256, 0, stream>>>(anchor, positive, negative, part, EHL, out);
  mdist_mfma<<<1024, 256, 0, stream>>>(EHL, out);
}

// Round 13
// 125.084 us; speedup vs baseline: 4.0110x; 1.4157x over previous
//
#include <hip/hip_runtime.h>
#include <hip/hip_bf16.h>

// MahalanobisDistanceLayer: B=8192, D=64.
// q = E @ E^T with E = (a-b) * rsqrt(var_per_feature(concat(a,b)+eps));
// out[i] = sum_j (q<0 ? 0 : sqrt(q)) + B*EPS_OUT for (anchor,positive), (anchor,negative).
//
// Split-bf16: E = Ehi + Elo -> K=192 bf16 GEMM on MFMA. Symmetric tile-pair scheme
// halves FLOPs: unordered 128-row tile pair {ib,(ib+s)&63} done once (s<=32, s=32 only
// ib<32); off-diag adds row-sums to ib-rows AND col-sums to jb-rows.
// 3 dispatches: stats(partials, no memset) -> prep(reduce+EHL) -> mdist.
// mdist: s-ring split 8 ways (s ≡ r mod 8) -> 1024 blocks; 32KB LDS + ~100 VGPR
// -> HW packs 4 blocks/CU NATURALLY. launch_bounds stays (256,2): forcing 4 waves/EU
// caps VGPR at 128 and spills the persistent A-frags (R7/R12 lesson: FETCH 200MB).

typedef short bf16x8 __attribute__((ext_vector_type(8)));
typedef unsigned short u16x8 __attribute__((ext_vector_type(8)));
typedef float f32x4 __attribute__((ext_vector_type(4)));

#define BROWS 8192
#define DFEAT 64
#define NCO   16384
#define EPS_IN  1e-4f
#define EPS_OUT 1e-6f
#define NPART 64

// ---- workspace layout (floats) ----
// [0, 24576)       : part[b][v] partials (64 blocks x 384), non-atomic
// [24576, +1M fl)  : EHL, 2 pairs x 8192 rows x 128 bf16 (row=[hi|lo], 256B),
//                    16B-chunk index XOR-swizzled by (row&7)
#define WS_EHL_F  24576
#define EHL_PAIR_USHORTS ((size_t)BROWS * 128)

static __device__ inline unsigned short f2bf_rne(float x) {
  unsigned u = __float_as_uint(x);
  unsigned r = (u + 0x7FFF + ((u >> 16) & 1)) >> 16;
  return (unsigned short)r;
}
static __device__ inline float bf2f(unsigned short s) {
  return __uint_as_float(((unsigned)s) << 16);
}

#define GLOAD(gsrc, ldst)                                                  \
  __builtin_amdgcn_global_load_lds(                                        \
      (const __attribute__((address_space(1))) void*)(gsrc),               \
      (__attribute__((address_space(3))) void*)(ldst), 16, 0, 0)

// ---------------------------------------------------------------------------
// Kernel A: per-block stats partials, NON-atomic (no zero-init needed).
// 64 blocks x 256 threads; block b covers rows [b*128, b*128+128).
__global__ __launch_bounds__(256) void stats_kernel(
    const float* __restrict__ a, const float* __restrict__ p,
    const float* __restrict__ n, float* __restrict__ part) {
  __shared__ float acc[384];
  int tid = threadIdx.x;
  int bid = blockIdx.x;
  for (int v = tid; v < 384; v += 256) acc[v] = 0.f;
  __syncthreads();
  const float4* A4 = (const float4*)a;
  const float4* P4 = (const float4*)p;
  const float4* N4 = (const float4*)n;
  size_t base = (size_t)bid * 2048 + tid;
  float s[3][4] = {}, q[3][4] = {};
  #pragma unroll
  for (int k = 0; k < 8; ++k) {
    size_t idx = base + k * 256;
    float4 va = A4[idx], vp = P4[idx], vn = N4[idx];
    float ea[4] = {va.x, va.y, va.z, va.w};
    float ep[4] = {vp.x, vp.y, vp.z, vp.w};
    float en[4] = {vn.x, vn.y, vn.z, vn.w};
    #pragma unroll
    for (int f = 0; f < 4; ++f) {
      float x0 = ea[f] + EPS_IN; s[0][f] += x0; q[0][f] += x0 * x0;
      float x1 = ep[f] + EPS_IN; s[1][f] += x1; q[1][f] += x1 * x1;
      float x2 = en[f] + EPS_IN; s[2][f] += x2; q[2][f] += x2 * x2;
    }
  }
  // lanes t, t^16, t^32, t^48 share feature group d0 = 4*(t&15)
  #pragma unroll
  for (int g = 0; g < 3; ++g)
    #pragma unroll
    for (int f = 0; f < 4; ++f) {
      float vs = s[g][f], vq = q[g][f];
      vs += __shfl_xor(vs, 16); vs += __shfl_xor(vs, 32);
      vq += __shfl_xor(vq, 16); vq += __shfl_xor(vq, 32);
      s[g][f] = vs; q[g][f] = vq;
    }
  int lane = tid & 63;
  if (lane < 16) {
    int d0 = lane * 4;
    #pragma unroll
    for (int g = 0; g < 3; ++g)
      #pragma unroll
      for (int f = 0; f < 4; ++f) {
        atomicAdd(&acc[(2 * g) * 64 + d0 + f], s[g][f]);
        atomicAdd(&acc[(2 * g + 1) * 64 + d0 + f], q[g][f]);
      }
  }
  __syncthreads();
  for (int v = tid; v < 384; v += 256)
    part[(size_t)bid * 384 + v] = acc[v];
}

// ---------------------------------------------------------------------------
// Kernel B: reduce partials in-block -> inv_std; build EHL rows [hi|lo] bf16,
// 16B chunks XOR-swizzled by row&7; pre-load out with 8192*EPS_OUT.
// Grid: 2 pairs x 256 row-tiles (32 rows each) = 512 blocks x 256 threads.
__global__ __launch_bounds__(256) void prep_kernel(
    const float* __restrict__ a, const float* __restrict__ p,
    const float* __restrict__ n, const float* __restrict__ part,
    unsigned short* __restrict__ EHL, float* __restrict__ out) {
  __shared__ float stats_s[384];
  __shared__ float is_s[64];
  int pair = blockIdx.x >> 8;
  int tb   = blockIdx.x & 255;
  int tid  = threadIdx.x;
  if (tid < 32) out[blockIdx.x * 32 + tid] = 8192.0f * EPS_OUT;
  // reduce part[0..63][v] -> stats_s[v]  (coalesced per iteration)
  {
    float s1 = 0.f, s2 = 0.f;
    for (int b = 0; b < NPART; ++b) {
      const float* pb = part + (size_t)b * 384;
      s1 += pb[tid];
      if (tid < 128) s2 += pb[256 + tid];
    }
    stats_s[tid] = s1;
    if (tid < 128) stats_s[256 + tid] = s2;
  }
  __syncthreads();
  if (tid < 64) {
    float sa = stats_s[tid], qa = stats_s[64 + tid];
    float sb = pair ? stats_s[256 + tid] : stats_s[128 + tid];
    float qb = pair ? stats_s[320 + tid] : stats_s[192 + tid];
    const float invN = 1.0f / (float)NCO;
    float m = (sa + sb) * invN;
    float v = (qa + qb) * invN - m * m;
    is_s[tid] = 1.0f / sqrtf(v);
  }
  __syncthreads();
  const float* bptr = pair ? n : p;
  unsigned short* dst = EHL + (size_t)pair * EHL_PAIR_USHORTS;
  int c0 = tid & 7;          // chunk within row (8 bf16 = 16B)
  int rl = tid >> 3;         // row within block (0..31)
  int row = tb * 32 + rl;
  int d0 = c0 * 8;
  const float* ar = a    + (size_t)row * DFEAT + d0;
  const float* br = bptr + (size_t)row * DFEAT + d0;
  float4 a0 = *(const float4*)(ar);
  float4 a1 = *(const float4*)(ar + 4);
  float4 b0 = *(const float4*)(br);
  float4 b1 = *(const float4*)(br + 4);
  float e[8] = {a0.x - b0.x, a0.y - b0.y, a0.z - b0.z, a0.w - b0.w,
                a1.x - b1.x, a1.y - b1.y, a1.z - b1.z, a1.w - b1.w};
  u16x8 vh, vl;
  #pragma unroll
  for (int j = 0; j < 8; ++j) {
    float ej = e[j] * is_s[d0 + j];
    unsigned short hi = f2bf_rne(ej);
    vh[j] = hi;
    vl[j] = f2bf_rne(ej - bf2f(hi));
  }
  int cs = c0 ^ (row & 7);
  char* drow = (char*)dst + (size_t)row * 256;
  *(u16x8*)(drow + cs * 16)       = vh;   // hi chunk
  *(u16x8*)(drow + (8 + cs) * 16) = vl;   // lo chunk
}

// ---------------------------------------------------------------------------
// Kernel C: symmetric MFMA GEMM. Block = (pair, ib, r): A tile (128 rows)
// persistent in registers; s = r, r+8, ... <= smax; each tile = two 64-row
// B substeps (16KB, double-buffered in the 32KB LDS after A-frag extraction).
// Grid: 2 x 64 x 8 = 1024 blocks x 256 threads, 32KB LDS, ~100 VGPR
// -> 4 blocks/CU packed by HW (no launch_bounds forcing -> no spill).
__global__ __launch_bounds__(256, 2) void mdist_mfma(
    const unsigned short* __restrict__ EHL, float* __restrict__ out) {
  __shared__ __align__(16) unsigned char smem[32768];
  unsigned char* sB0 = smem;
  unsigned char* sB1 = smem + 16384;
  int bid = blockIdx.x;
  int sw  = (bid & 7) * 128 + (bid >> 3);  // XCD swizzle (1024 = 8*128)
  int pair = sw >> 9;
  int ib   = (sw >> 3) & 63;
  int r0   = sw & 7;                       // s ≡ r0 (mod 8)
  const char* base = (const char*)(EHL + (size_t)pair * EHL_PAIR_USHORTS);
  const char* gA = base + (size_t)ib * 32768;
  int tid = threadIdx.x;
  int smax = (ib < 32) ? 32 : 31;
  int nT   = ((smax - r0) / 8 + 1) * 2;    // substeps (8 or 10)

  // stage A (32KB) into the whole smem
  #pragma unroll
  for (int rr = 0; rr < 8; ++rr) {
    int off = rr * 4096 + tid * 16;
    GLOAD(gA + off, smem + off);
  }
  __syncthreads();

  int lane = tid & 63, w = tid >> 6;
  int wr = w >> 1, wc = w & 1;             // wave tile: rows wr*64, cols wc*32
  int l15 = lane & 15, lg = lane >> 4;

  // A fragments, resident for whole kernel: af[hk][m], hk = (half_sel<<1)|ks
  bf16x8 af[4][4];
  #pragma unroll
  for (int hk = 0; hk < 4; ++hk) {
    int c = ((hk >> 1) << 3) | ((hk & 1) << 2) | lg;
    #pragma unroll
    for (int m = 0; m < 4; ++m) {
      int rr = wr * 64 + m * 16 + l15;
      int cs = c ^ (rr & 7);
      af[hk][m] = *(const bf16x8*)(smem + rr * 256 + cs * 16);
    }
  }
  __syncthreads();   // all af reads done -> smem free for B staging

  // stage B substep 0 -> sB0
  {
    const char* gB0 = base + (size_t)((ib + r0) & 63) * 32768;
    #pragma unroll
    for (int rr = 0; rr < 4; ++rr) {
      int off = rr * 4096 + tid * 16;
      GLOAD(gB0 + off, sB0 + off);
    }
  }
  __syncthreads();

  float rs[4][4];
  #pragma unroll
  for (int m = 0; m < 4; ++m)
    #pragma unroll
    for (int rr = 0; rr < 4; ++rr) rs[m][rr] = 0.f;

  const f32x4 zacc = {0.f, 0.f, 0.f, 0.f};
  const int AH[3] = {0, 0, 1};
  const int BH[3] = {0, 1, 0};

  for (int t = 0; t < nT; ++t) {
    unsigned char* wbuf = (t & 1) ? sB0 : sB1;        // receives B(t+1)
    const unsigned char* rbuf = (t & 1) ? sB1 : sB0;  // holds B(t)
    int s   = r0 + 8 * (t >> 1);
    int sub = t & 1;
    if (t + 1 < nT) {
      int tn = t + 1;
      int sn = r0 + 8 * (tn >> 1);
      const char* gs = base + (size_t)((ib + sn) & 63) * 32768 + (tn & 1) * 16384;
      #pragma unroll
      for (int rr = 0; rr < 4; ++rr) {
        int off = rr * 4096 + tid * 16;
        GLOAD(gs + off, wbuf + off);
      }
    }
    bf16x8 bf[4][2];
    #pragma unroll
    for (int hk = 0; hk < 4; ++hk) {
      int c = ((hk >> 1) << 3) | ((hk & 1) << 2) | lg;
      #pragma unroll
      for (int nn = 0; nn < 2; ++nn) {
        int rr = wc * 32 + nn * 16 + l15;
        int cs = c ^ (rr & 7);
        bf[hk][nn] = *(const bf16x8*)(rbuf + rr * 256 + cs * 16);
      }
    }
    f32x4 acc[4][2];
    #pragma unroll
    for (int tt = 0; tt < 3; ++tt) {
      #pragma unroll
      for (int ks = 0; ks < 2; ++ks) {
        int ahk = (AH[tt] << 1) | ks;
        int bhk = (BH[tt] << 1) | ks;
        #pragma unroll
        for (int m = 0; m < 4; ++m) {
          #pragma unroll
          for (int nn = 0; nn < 2; ++nn)
            acc[m][nn] = __builtin_amdgcn_mfma_f32_16x16x32_bf16(
                af[ahk][m], bf[bhk][nn],
                (tt == 0 && ks == 0) ? zacc : acc[m][nn], 0, 0, 0);
        }
      }
    }
    // epilogue: f = sqrt(max(q,0)); rows always; cols for off-diag tiles
    if (s == 0) {
      #pragma unroll
      for (int m = 0; m < 4; ++m)
        #pragma unroll
        for (int nn = 0; nn < 2; ++nn)
          #pragma unroll
          for (int rr = 0; rr < 4; ++rr)
            rs[m][rr] += __builtin_amdgcn_sqrtf(fmaxf(acc[m][nn][rr], 0.f));
    } else {
      float cq0 = 0.f, cq1 = 0.f;
      #pragma unroll
      for (int m = 0; m < 4; ++m)
        #pragma unroll
        for (int nn = 0; nn < 2; ++nn)
          #pragma unroll
          for (int rr = 0; rr < 4; ++rr) {
            float f = __builtin_amdgcn_sqrtf(fmaxf(acc[m][nn][rr], 0.f));
            rs[m][rr] += f;
            if (nn == 0) cq0 += f; else cq1 += f;
          }
      cq0 += __shfl_xor(cq0, 16); cq0 += __shfl_xor(cq0, 32);
      cq1 += __shfl_xor(cq1, 16); cq1 += __shfl_xor(cq1, 32);
      if (lane < 16) {
        int jb = (ib + s) & 63;
        float* orow = &out[pair * BROWS + jb * 128 + sub * 64 + wc * 32 + l15];
        atomicAdd(orow, cq0);
        atomicAdd(orow + 16, cq1);
      }
    }
    __syncthreads();
  }

  // final row-sum reduce over the 16 col-lanes, one atomic per row per wave
  #pragma unroll
  for (int m = 0; m < 4; ++m)
    #pragma unroll
    for (int rr = 0; rr < 4; ++rr) {
      float v = rs[m][rr];
      v += __shfl_xor(v, 1);
      v += __shfl_xor(v, 2);
      v += __shfl_xor(v, 4);
      v += __shfl_xor(v, 8);
      rs[m][rr] = v;
    }
  if (l15 == 0) {
    int i0 = ib * 128 + wr * 64;
    #pragma unroll
    for (int m = 0; m < 4; ++m)
      #pragma unroll
      for (int rr = 0; rr < 4; ++rr)
        atomicAdd(&out[pair * BROWS + i0 + m * 16 + lg * 4 + rr], rs[m][rr]);
  }
}

// ---------------------------------------------------------------------------
extern "C" void kernel_launch(void* const* d_in, const int* in_sizes, int n_in,
                              void* d_out, int out_size, void* d_ws, size_t ws_size,
                              hipStream_t stream) {
  const float* anchor   = (const float*)d_in[0];
  const float* positive = (const float*)d_in[1];
  const float* negative = (const float*)d_in[2];
  float* out = (float*)d_out;
  float* ws  = (float*)d_ws;

  float* part = ws;
  unsigned short* EHL = (unsigned short*)(ws + WS_EHL_F);

  stats_kernel<<<64, 256, 0, stream>>>(anchor, positive, negative, part);
  prep_kernel<<<512, 256, 0, stream>>>(anchor, positive, negative, part, EHL, out);
  mdist_mfma<<<1024, 256, 0, stream>>>(EHL, out);
}